// Round 4
// baseline (513.757 us; speedup 1.0000x reference)
//
#include <hip/hip_runtime.h>

// CenterLoss: loss = (1/B) * sum_j [ (sum_{i:l_i=j} ||f_i - c_j||^2) / (n_j * D) ]
// B=65536, D=512, C=1000, fp32 in / fp32 scalar out.
// Memory-bound: 128 MiB feature read -> ~21 us kernel floor at 6.3 TB/s.
//
// Round-3 lesson: cooperative grid.sync costs ~100us each on gfx950 (322us
// kernel with ZERO hbm dependence). Instead: single streaming kernel with
// fp32 atomics into sums/counts + last-block-done ticket finalize.
// 2 dispatches total: tiny memset + fused kernel.

#define WAVE 64
constexpr int THREADS = 256;
constexpr int WAVES_PER_BLOCK = THREADS / WAVE;   // 4
constexpr int NBLOCKS = 2048;                     // 8192 waves = 32 waves/CU (full)

__global__ __launch_bounds__(THREADS) void centerloss_kernel(
    const float* __restrict__ features,   // [batch, feat]
    const float* __restrict__ centers,    // [nclass, feat]
    const int*   __restrict__ labels,     // [batch]
    float* __restrict__ sums,             // [nclass]  (ws, zeroed)
    float* __restrict__ counts,           // [nclass]  (ws, zeroed)
    unsigned* __restrict__ ticket,        // [1]       (ws, zeroed)
    float* __restrict__ out,              // [1]
    int batch, int feat, int nclass)
{
    const int wib    = threadIdx.x >> 6;
    const int lane   = threadIdx.x & 63;
    const int gwave  = blockIdx.x * WAVES_PER_BLOCK + wib;
    const int nwaves = gridDim.x * WAVES_PER_BLOCK;  // 8192
    const int n4     = feat >> 2;                    // 128 float4 per row

    // ---- streaming phase: one wave per sample row ----
    for (int sample = gwave; sample < batch; sample += nwaves) {
        const int label = labels[sample];
        const float4* __restrict__ f4 =
            (const float4*)(features + (size_t)sample * feat);
        const float4* __restrict__ c4 =
            (const float4*)(centers + (size_t)label * feat);

        float acc = 0.0f;
#pragma unroll 2
        for (int idx = lane; idx < n4; idx += WAVE) {
            float4 fv = f4[idx];
            float4 cv = c4[idx];
            float dx = fv.x - cv.x;
            float dy = fv.y - cv.y;
            float dz = fv.z - cv.z;
            float dw = fv.w - cv.w;
            acc += dx * dx + dy * dy + dz * dz + dw * dw;
        }
        // wave-64 butterfly reduce
#pragma unroll
        for (int off = 32; off > 0; off >>= 1)
            acc += __shfl_down(acc, off, WAVE);

        if (lane == 0) {
            atomicAdd(&sums[label], acc);
            atomicAdd(&counts[label], 1.0f);
        }
    }

    // ---- last-block-done finalize (no grid.sync) ----
    __threadfence();            // release: my atomics visible device-wide
    __syncthreads();            // all waves of this block done
    __shared__ int is_last;
    if (threadIdx.x == 0) {
        unsigned old = atomicAdd(ticket, 1u);
        is_last = (old == (unsigned)(gridDim.x - 1));
    }
    __syncthreads();
    if (!is_last) return;

    __threadfence();            // acquire: see all other blocks' atomics
    float total = 0.0f;
    for (int j = threadIdx.x; j < nclass; j += THREADS) {
        float n = __hip_atomic_load(&counts[j], __ATOMIC_RELAXED,
                                    __HIP_MEMORY_SCOPE_AGENT);
        float s = __hip_atomic_load(&sums[j], __ATOMIC_RELAXED,
                                    __HIP_MEMORY_SCOPE_AGENT);
        if (n > 0.5f) total += s / n;
    }
#pragma unroll
    for (int off = 32; off > 0; off >>= 1)
        total += __shfl_down(total, off, WAVE);

    __shared__ float wpart[WAVES_PER_BLOCK];
    if (lane == 0) wpart[wib] = total;
    __syncthreads();
    if (threadIdx.x == 0) {
        float t = 0.0f;
#pragma unroll
        for (int w = 0; w < WAVES_PER_BLOCK; ++w) t += wpart[w];
        out[0] = t / ((float)feat * (float)batch);
    }
}

extern "C" void kernel_launch(void* const* d_in, const int* in_sizes, int n_in,
                              void* d_out, int out_size, void* d_ws, size_t ws_size,
                              hipStream_t stream) {
    const float* features = (const float*)d_in[0];
    const float* centers  = (const float*)d_in[1];
    const int*   labels   = (const int*)d_in[2];

    const int batch  = in_sizes[2];                 // 65536
    const int feat   = in_sizes[0] / batch;         // 512
    const int nclass = in_sizes[1] / feat;          // 1000

    float*    sums   = (float*)d_ws;
    float*    counts = sums + nclass;
    unsigned* ticket = (unsigned*)(counts + nclass);

    // zero sums + counts + ticket (ws is poisoned to 0xAA before every call)
    hipMemsetAsync(d_ws, 0, (size_t)(2 * nclass + 1) * sizeof(float), stream);

    centerloss_kernel<<<NBLOCKS, THREADS, 0, stream>>>(
        features, centers, labels, sums, counts, ticket,
        (float*)d_out, batch, feat, nclass);
}

// Round 5
// 194.187 us; speedup vs baseline: 2.6457x; 2.6457x over previous
//
#include <hip/hip_runtime.h>

// CenterLoss: loss = (1/B) * sum_j [ (sum_{i:l_i=j} ||f_i - c_j||^2) / (n_j * D) ]
// B=65536, D=512, C=1000, fp32 in / fp32 scalar out.
//
// Lessons so far:
//   R1 (memset + dist-with-atomics + finalize, 3 dispatches): chain ~46us. BEST.
//   R2 (+1 dispatch): +22us -> dispatches cost real time.
//   R3 (grid.sync) / R4 (threadfence+ticket): 322/377us REGARDLESS of HBM
//   traffic -> device-scope fences flush per-XCD L2; never use them here.
// This round: R1 structure, 4-way replicated accumulators to cut atomic
// contention, identical streaming interior (1 wave per sample row, float4).
// Floor: 146us harness reset (in timed window) + ~21us HBM + dispatch odds.

#define WAVE 64
constexpr int THREADS = 256;
constexpr int WAVES_PER_BLOCK = THREADS / WAVE;   // 4
constexpr int NREP = 4;                           // accumulator replicas

__global__ __launch_bounds__(THREADS) void dist_kernel(
    const float* __restrict__ features,   // [batch, feat]
    const float* __restrict__ centers,    // [nclass, feat]
    const int*   __restrict__ labels,     // [batch]
    float* __restrict__ acc_ws,           // [NREP][2][nclass] zeroed: sums,counts
    int batch, int feat, int nclass)
{
    const int wib    = threadIdx.x >> 6;
    const int lane   = threadIdx.x & 63;
    const int sample = blockIdx.x * WAVES_PER_BLOCK + wib;
    if (sample >= batch) return;

    const int label = labels[sample];
    const float4* __restrict__ f4 =
        (const float4*)(features + (size_t)sample * feat);
    const float4* __restrict__ c4 =
        (const float4*)(centers + (size_t)label * feat);

    const int n4 = feat >> 2;                     // 128 float4 per row
    float acc = 0.0f;
#pragma unroll 2
    for (int idx = lane; idx < n4; idx += WAVE) {
        float4 fv = f4[idx];
        float4 cv = c4[idx];
        float dx = fv.x - cv.x;
        float dy = fv.y - cv.y;
        float dz = fv.z - cv.z;
        float dw = fv.w - cv.w;
        acc += dx * dx + dy * dy + dz * dz + dw * dw;
    }

    // wave-64 butterfly reduce
#pragma unroll
    for (int off = 32; off > 0; off >>= 1)
        acc += __shfl_down(acc, off, WAVE);

    if (lane == 0) {
        float* rep = acc_ws + (size_t)(blockIdx.x & (NREP - 1)) * 2 * nclass;
        atomicAdd(&rep[label], acc);              // sums
        atomicAdd(&rep[nclass + label], 1.0f);    // counts
    }
}

__global__ __launch_bounds__(THREADS) void finalize_kernel(
    const float* __restrict__ acc_ws,     // [NREP][2][nclass]
    float* __restrict__ out,
    int nclass, int feat, int batch)
{
    float total = 0.0f;
    for (int j = threadIdx.x; j < nclass; j += THREADS) {
        float s = 0.0f, n = 0.0f;
#pragma unroll
        for (int r = 0; r < NREP; ++r) {
            const float* rep = acc_ws + (size_t)r * 2 * nclass;
            s += rep[j];
            n += rep[nclass + j];
        }
        if (n > 0.5f) total += s / n;
    }
#pragma unroll
    for (int off = 32; off > 0; off >>= 1)
        total += __shfl_down(total, off, WAVE);

    __shared__ float wpart[WAVES_PER_BLOCK];
    const int lane = threadIdx.x & 63;
    const int wib  = threadIdx.x >> 6;
    if (lane == 0) wpart[wib] = total;
    __syncthreads();
    if (threadIdx.x == 0) {
        float t = 0.0f;
#pragma unroll
        for (int w = 0; w < WAVES_PER_BLOCK; ++w) t += wpart[w];
        out[0] = t / ((float)feat * (float)batch);
    }
}

extern "C" void kernel_launch(void* const* d_in, const int* in_sizes, int n_in,
                              void* d_out, int out_size, void* d_ws, size_t ws_size,
                              hipStream_t stream) {
    const float* features = (const float*)d_in[0];
    const float* centers  = (const float*)d_in[1];
    const int*   labels   = (const int*)d_in[2];

    const int batch  = in_sizes[2];                 // 65536
    const int feat   = in_sizes[0] / batch;         // 512
    const int nclass = in_sizes[1] / feat;          // 1000

    float* acc_ws = (float*)d_ws;                   // NREP * 2 * nclass floats

    hipMemsetAsync(acc_ws, 0, (size_t)NREP * 2 * nclass * sizeof(float), stream);

    const int nblocks = (batch + WAVES_PER_BLOCK - 1) / WAVES_PER_BLOCK; // 16384
    dist_kernel<<<nblocks, THREADS, 0, stream>>>(
        features, centers, labels, acc_ws, batch, feat, nclass);

    finalize_kernel<<<1, THREADS, 0, stream>>>(
        acc_ws, (float*)d_out, nclass, feat, batch);
}